// Round 9
// baseline (142.426 us; speedup 1.0000x reference)
//
#include <hip/hip_runtime.h>
#include <hip/hip_bf16.h>

typedef __attribute__((ext_vector_type(8))) short short8;   // 8 bf16 (4 VGPRs)
typedef __attribute__((ext_vector_type(4))) float f32x4;    // MFMA acc

// Problem constants
static constexpr int HW = 1024;   // 32*32
static constexpr int C2 = 160;    // corr channel count
static constexpr int FS = 168;    // corr/epilogue LDS row stride in shorts (336 B)
static constexpr int XBS = 42;    // conv xB row stride in shorts (odd dword stride)
static constexpr int WPLANE = 160 * 40;  // shorts per (ks,mat,hl) w-plane
static constexpr int WKS = 4 * WPLANE;
static constexpr int KSTEPS = 10;
static constexpr size_t PL = 32ull * 1024 * 160;   // shorts per f-plane (10.49MB)
static constexpr size_t PPL = 32ull * 256 * 160;   // shorts per pooled plane

__device__ inline short bfh(float v) {
  __hip_bfloat16 h = __float2bfloat16(v);
  return *reinterpret_cast<short*>(&h);
}
__device__ inline float bff(short s) {
  union { unsigned u; float f; } c;
  c.u = ((unsigned)(unsigned short)s) << 16;
  return c.f;
}
__device__ inline unsigned packhl(float v0, float v1, unsigned& lo) {
  const short h0 = bfh(v0), h1 = bfh(v1);
  const short l0 = bfh(v0 - bff(h0)), l1 = bfh(v1 - bff(h1));
  lo = (unsigned)(unsigned short)l0 | ((unsigned)(unsigned short)l1 << 16);
  return (unsigned)(unsigned short)h0 | ((unsigned)(unsigned short)h1 << 16);
}
// dword-aligned (not 16B-aligned) LDS short8 load as 4x b32
__device__ inline short8 ld8_b32(const short* p) {
  const unsigned* q = reinterpret_cast<const unsigned*>(p);
  union { unsigned u[4]; short8 s; } U;
  U.u[0] = q[0]; U.u[1] = q[1]; U.u[2] = q[2]; U.u[3] = q[3];
  return U.s;
}

// ---------------------------------------------------------------------------
// Kernel 0: pre-split w into bf16 (hi,lo) planes, tiled per k-step (unchanged).
// ---------------------------------------------------------------------------
__global__ __launch_bounds__(256)
void wprep_kernel(const float* __restrict__ w0, const float* __restrict__ w1,
                  short* __restrict__ wp) {
  const int id = blockIdx.x * 256 + threadIdx.x;
  if (id >= KSTEPS * WKS) return;
  const int kk = id % 40;
  const int o = (id / 40) % 160;
  const int hl = (id / 6400) % 2;
  const int mat = (id / 12800) % 2;
  const int ks = id / 25600;
  short outv = 0;
  if (kk < 32) {
    const float v = (mat ? w1 : w0)[o * 320 + ks * 32 + kk];
    const short hb = bfh(v);
    outv = hl ? bfh(v - bff(hb)) : hb;
  }
  wp[id] = outv;
}

// ---------------------------------------------------------------------------
// Kernel 1: fused 1x1 convs (round-8 structure; verified output layout).
// ROUND-9 CHANGE: staging software-pipelined through REGISTERS across ks.
// LOADX/LOADA(ks+1) issue right after the stage barrier (whole MFMA phase +
// barrier to cover latency); STAGE(ks) converts/writes from registers only.
// Double-buffered via named arrays in an unrolled 2-phase loop (no runtime
// indexing). MFMA phase, epilogue, output layout byte-identical to round 8.
// ---------------------------------------------------------------------------
__global__ __launch_bounds__(256)
void conv_fused(const float* __restrict__ x, const short* __restrict__ wprep,
                short* __restrict__ f0bh, short* __restrict__ f0bl,
                short* __restrict__ f1bh, short* __restrict__ f1bl) {
  __shared__ __align__(16) short xB[2][288 * XBS];  // [hl][col=f*32+px][kk]
  __shared__ __align__(16) short aL[2][80 * 40];    // [hl][gr][kk]
  const int pxt = blockIdx.x;  // 0..31
  const int qp = blockIdx.y;   // 0..3
  const int bb = blockIdx.z;   // 0..3
  const int tid = threadIdx.x;
  const int lane = tid & 63;
  const int wave = __builtin_amdgcn_readfirstlane(tid >> 6);
  const int lr = lane & 15, kg = lane >> 4;
  const int pxh = wave & 1;   // px half (16)
  const int fpar = wave >> 1; // frame parity: f in {fpar, fpar+2, ...}

  f32x4 acc[5][5];
#pragma unroll
  for (int mt = 0; mt < 5; ++mt)
#pragma unroll
    for (int fi = 0; fi < 5; ++fi)
#pragma unroll
      for (int r = 0; r < 4; ++r) acc[mt][fi][r] = 0.f;

  const size_t xbase = (size_t)bb * 320 * 9216 + (size_t)pxt * 32;

  float2 xrA[18], xrB[18];
  uint4 arA[4], arB[4];

#define LOADX(KS, XR)                                                         \
  {                                                                           \
    _Pragma("unroll") for (int i = 0; i < 18; ++i) {                          \
      const int id_ = tid + i * 256;                                          \
      const int px_ = id_ & 31, f_ = (id_ >> 5) % 9, kl2_ = id_ / 288;        \
      const float* xp_ =                                                      \
          x + xbase + (size_t)((KS)*32 + 2 * kl2_) * 9216 + f_ * 1024 + px_;  \
      XR[i].x = xp_[0];                                                       \
      XR[i].y = xp_[9216];                                                    \
    }                                                                         \
  }
#define LOADA(KS, AR)                                                         \
  {                                                                           \
    _Pragma("unroll") for (int i = 0; i < 4; ++i) {                           \
      const int idx_ = tid + i * 256;                                         \
      if (idx_ < 800) {                                                       \
        const int u_ = idx_ % 5, gr_ = (idx_ / 5) % 80, hl_ = idx_ / 400;     \
        const int mat_ = gr_ >= 40;                                           \
        const int o_ = qp * 40 + (gr_ - mat_ * 40);                           \
        AR[i] = reinterpret_cast<const uint4*>(                               \
            wprep + (size_t)(((KS)*2 + mat_) * 2 + hl_) * WPLANE + o_ * 40)[u_]; \
      }                                                                       \
    }                                                                         \
  }
#define STAGE(XR, AR)                                                         \
  {                                                                           \
    _Pragma("unroll") for (int i = 0; i < 4; ++i) {                           \
      const int idx_ = tid + i * 256;                                         \
      if (idx_ < 800) {                                                       \
        const int u_ = idx_ % 5, gr_ = (idx_ / 5) % 80, hl_ = idx_ / 400;     \
        reinterpret_cast<uint4*>(&aL[hl_][gr_ * 40])[u_] = AR[i];             \
      }                                                                       \
    }                                                                         \
    _Pragma("unroll") for (int i = 0; i < 18; ++i) {                          \
      const int id_ = tid + i * 256;                                          \
      const int px_ = id_ & 31, f_ = (id_ >> 5) % 9, kl2_ = id_ / 288;        \
      unsigned lo_;                                                           \
      const unsigned hp_ = packhl(XR[i].x, XR[i].y, lo_);                     \
      *reinterpret_cast<unsigned*>(&xB[0][(f_ * 32 + px_) * XBS + 2 * kl2_]) = hp_; \
      *reinterpret_cast<unsigned*>(&xB[1][(f_ * 32 + px_) * XBS + 2 * kl2_]) = lo_; \
    }                                                                         \
  }
#define MFMA_PHASE(KS)                                                        \
  {                                                                           \
    short8 Ah[5], Al[5];                                                      \
    _Pragma("unroll") for (int mt = 0; mt < 5; ++mt) {                        \
      Ah[mt] = *reinterpret_cast<const short8*>(&aL[0][(mt * 16 + lr) * 40 + kg * 8]); \
      Al[mt] = *reinterpret_cast<const short8*>(&aL[1][(mt * 16 + lr) * 40 + kg * 8]); \
    }                                                                         \
    _Pragma("unroll") for (int fi = 0; fi < 5; ++fi) {                        \
      if (2 * fi + fpar < 9) {                                                \
        const int f_ = 2 * fi + fpar;                                         \
        const int col_ = (f_ * 32 + pxh * 16 + lr) * XBS + kg * 8;            \
        const short8 Bh = ld8_b32(&xB[0][col_]);                              \
        const short8 Bl = ld8_b32(&xB[1][col_]);                              \
        _Pragma("unroll") for (int mt = 0; mt < 5; ++mt) {                    \
          acc[mt][fi] = __builtin_amdgcn_mfma_f32_16x16x32_bf16(Ah[mt], Bh, acc[mt][fi], 0, 0, 0); \
          acc[mt][fi] = __builtin_amdgcn_mfma_f32_16x16x32_bf16(Ah[mt], Bl, acc[mt][fi], 0, 0, 0); \
          acc[mt][fi] = __builtin_amdgcn_mfma_f32_16x16x32_bf16(Al[mt], Bh, acc[mt][fi], 0, 0, 0); \
        }                                                                     \
      }                                                                       \
    }                                                                         \
  }

  // prologue: load ks=0
  LOADX(0, xrA);
  LOADA(0, arA);

#pragma unroll
  for (int ks2 = 0; ks2 < 5; ++ks2) {
    const int ksA = 2 * ks2;
    // phase A: stage ksA from (xrA, arA); prefetch ksA+1 into (xrB, arB)
    __syncthreads();  // previous MFMA readers done
    STAGE(xrA, arA);
    __syncthreads();
    LOADX(ksA + 1, xrB);
    LOADA(ksA + 1, arB);
    MFMA_PHASE(ksA);
    // phase B: stage ksA+1 from (xrB, arB); prefetch ksA+2 into (xrA, arA)
    __syncthreads();
    STAGE(xrB, arB);
    __syncthreads();
    if (ks2 < 4) {
      LOADX(ksA + 2, xrA);
      LOADA(ksA + 2, arA);
    }
    MFMA_PHASE(ksA + 1);
  }
#undef LOADX
#undef LOADA
#undef STAGE
#undef MFMA_PHASE

  // ---- epilogue: two mat-passes through LDS transpose (tL overlays xB) ----
  short* tL = &xB[0][0];  // [2 planes][64 rows][168]
#pragma unroll
  for (int m = 0; m < 2; ++m) {
    __syncthreads();  // previous readers of xB/tL done
#pragma unroll
    for (int mt = 0; mt < 5; ++mt)
#pragma unroll
      for (int fi = 0; fi < 5; ++fi) {
        const int f = 2 * fi + fpar;
        const int tt = f - m;
        if (f < 9 && (unsigned)tt < 8u) {
#pragma unroll
          for (int rr = 0; rr < 4; ++rr) {
            const int gr = mt * 16 + kg * 4 + rr;
            if ((gr >= 40) == (m == 1)) {  // row belongs to this mat
              const int rowl = gr - m * 40;
              const int ql = rowl / 20, r20 = rowl % 20;
              const int c = 8 * r20 + tt;
              const int row = ql * 32 + pxh * 16 + lr;
              const float v = acc[mt][fi][rr];
              const short h = bfh(v);
              const short l = bfh(v - bff(h));
              tL[row * FS + c] = h;
              tL[10752 + row * FS + c] = l;
            }
          }
        }
      }
    __syncthreads();
    // coalesced copy-out: 2560 uint4
#pragma unroll
    for (int i = 0; i < 10; ++i) {
      const int idx = tid + i * 256;
      const int plane = idx / 1280, rem = idx % 1280;
      const int row = rem / 20, c16 = rem % 20;
      const int ql = row >> 5, pxl = row & 31;
      const int n = bb * 8 + qp * 2 + ql;
      short* dst = (m == 0) ? (plane ? f0bl : f0bh) : (plane ? f1bl : f1bh);
      *reinterpret_cast<uint4*>(dst + ((size_t)n * 1024 + pxt * 32 + pxl) * 160 + c16 * 8) =
          *reinterpret_cast<const uint4*>(&tL[plane * 10752 + row * FS + c16 * 8]);
    }
  }
}

// ---------------------------------------------------------------------------
// Kernel 2: 2x2 avg-pool on the bf16 h/l planes (unchanged)
// ---------------------------------------------------------------------------
__global__ __launch_bounds__(256)
void pool_b(const short* __restrict__ f1bh, const short* __restrict__ f1bl,
            short* __restrict__ g1pbh, short* __restrict__ g1pbl) {
  const int id = blockIdx.x * 256 + threadIdx.x;  // 32*256*20
  if (id >= 32 * 256 * 20) return;
  const int c16 = id % 20;
  const int PX = (id / 20) & 255;
  const int n = id / (20 * 256);
  const int Y = PX >> 4, X = PX & 15;
  const int r0 = Y * 64 + X * 2;
  const size_t base = ((size_t)n * 1024 + r0) * 160 + c16 * 8;
  const short8 h00 = *reinterpret_cast<const short8*>(f1bh + base);
  const short8 h01 = *reinterpret_cast<const short8*>(f1bh + base + 160);
  const short8 h10 = *reinterpret_cast<const short8*>(f1bh + base + 32 * 160);
  const short8 h11 = *reinterpret_cast<const short8*>(f1bh + base + 33 * 160);
  const short8 l00 = *reinterpret_cast<const short8*>(f1bl + base);
  const short8 l01 = *reinterpret_cast<const short8*>(f1bl + base + 160);
  const short8 l10 = *reinterpret_cast<const short8*>(f1bl + base + 32 * 160);
  const short8 l11 = *reinterpret_cast<const short8*>(f1bl + base + 33 * 160);
  short8 ho, lo;
#pragma unroll
  for (int j = 0; j < 8; ++j) {
    const float v = 0.25f * ((bff(h00[j]) + bff(l00[j])) + (bff(h01[j]) + bff(l01[j])) +
                             (bff(h10[j]) + bff(l10[j])) + (bff(h11[j]) + bff(l11[j])));
    const short h = bfh(v);
    ho[j] = h;
    lo[j] = bfh(v - bff(h));
  }
  const size_t ob = ((size_t)n * 256 + PX) * 160 + c16 * 8;
  *reinterpret_cast<short8*>(g1pbh + ob) = ho;
  *reinterpret_cast<short8*>(g1pbl + ob) = lo;
}

// ---------------------------------------------------------------------------
// Kernel 3: correlation + pyramid sampling via split-bf16 MFMA
// (unchanged from round 6 — verified; XCD swizzle kept)
// ---------------------------------------------------------------------------
__global__ __launch_bounds__(256)
void corr_kernel(const short* __restrict__ f0bh, const short* __restrict__ f0bl,
                 const short* __restrict__ f1bh, const short* __restrict__ f1bl,
                 const short* __restrict__ g1pbh, const short* __restrict__ g1pbl,
                 float* __restrict__ out) {
  __shared__ __align__(16) short f0L[2][32 * FS];
  __shared__ __align__(16) short f1L[2][32 * FS];
  __shared__ float S0[32 * 33];
  __shared__ float S1[2][32 * 17];
  const int flat = blockIdx.x;
  const int xcd = flat & 7;
  const int rr_ = flat >> 3;
  const int y = rr_ & 31;                 // 0..31
  const int n = (xcd << 2) | (rr_ >> 5);  // 0..31
  const int bb = n >> 3, q = n & 7;
  const int tid = threadIdx.x;
  const int lane = tid & 63;
  const int wave = __builtin_amdgcn_readfirstlane(tid >> 6);
  const int lr = lane & 15, kg = lane >> 4;
  const int xx = tid & 31;
  const int hi = tid >> 5;  // 0..7
  const float inv = 1.f / 160.f;
  const size_t obase = (size_t)(bb * 784 + q) * 1024 + (size_t)y * 32;

  // ---- stage f0 row: plain uint4 copies ----
#pragma unroll
  for (int i = 0; i < 5; ++i) {
    const int idx = tid + i * 256;  // < 1280
    const int plane = idx / 640, rem = idx % 640;
    const int px = rem / 20, c16 = rem % 20;
    const short* src = (plane ? f0bl : f0bh) + ((size_t)n * 1024 + y * 32 + px) * 160 + c16 * 8;
    *reinterpret_cast<uint4*>(&f0L[plane][px * FS + c16 * 8]) =
        *reinterpret_cast<const uint4*>(src);
  }
  __syncthreads();

  // ---- hoist A-fragments ----
  const int mi0 = wave >> 1, ni0 = wave & 1;
  short8 a0h[5], a0l[5];
#pragma unroll
  for (int ks = 0; ks < 5; ++ks) {
    a0h[ks] = *reinterpret_cast<const short8*>(&f0L[0][(mi0 * 16 + lr) * FS + ks * 32 + kg * 8]);
    a0l[ks] = *reinterpret_cast<const short8*>(&f0L[1][(mi0 * 16 + lr) * FS + ks * 32 + kg * 8]);
  }

  // ---- level 0 ----
  for (int dyi = 0; dyi < 7; ++dyi) {
    const int yy = y + dyi - 3;
    const bool inr = (unsigned)yy < 32u;
    __syncthreads();
    if (inr) {
#pragma unroll
      for (int i = 0; i < 5; ++i) {
        const int idx = tid + i * 256;
        const int plane = idx / 640, rem = idx % 640;
        const int px = rem / 20, c16 = rem % 20;
        const short* src = (plane ? f1bl : f1bh) + ((size_t)n * 1024 + yy * 32 + px) * 160 + c16 * 8;
        *reinterpret_cast<uint4*>(&f1L[plane][px * FS + c16 * 8]) =
            *reinterpret_cast<const uint4*>(src);
      }
    }
    __syncthreads();
    if (inr) {
      f32x4 aA = {0.f, 0.f, 0.f, 0.f}, aB = aA, aC = aA;
#pragma unroll
      for (int ks = 0; ks < 5; ++ks) {
        const short8 bh = *reinterpret_cast<const short8*>(&f1L[0][(ni0 * 16 + lr) * FS + ks * 32 + kg * 8]);
        const short8 bl = *reinterpret_cast<const short8*>(&f1L[1][(ni0 * 16 + lr) * FS + ks * 32 + kg * 8]);
        aA = __builtin_amdgcn_mfma_f32_16x16x32_bf16(a0h[ks], bh, aA, 0, 0, 0);
        aB = __builtin_amdgcn_mfma_f32_16x16x32_bf16(a0h[ks], bl, aB, 0, 0, 0);
        aC = __builtin_amdgcn_mfma_f32_16x16x32_bf16(a0l[ks], bh, aC, 0, 0, 0);
      }
#pragma unroll
      for (int r = 0; r < 4; ++r)
        S0[(mi0 * 16 + kg * 4 + r) * 33 + ni0 * 16 + lr] = (aA[r] + aB[r]) + aC[r];
    }
    __syncthreads();
    if (hi < 7) {
      const int x2 = xx + hi - 3;
      const float val = (inr && (unsigned)x2 < 32u) ? S0[xx * 33 + x2] * inv : 0.f;
      out[obase + (size_t)(hi * 7 + dyi) * 8192 + xx] = val;
    }
  }

  // ---- level 1: corner dots on pooled planes, rolling S1 + fused combine ----
  short8 a1h[5], a1l[5];
  if (wave < 2) {
#pragma unroll
    for (int ks = 0; ks < 5; ++ks) {
      a1h[ks] = *reinterpret_cast<const short8*>(&f0L[0][(wave * 16 + lr) * FS + ks * 32 + kg * 8]);
      a1l[ks] = *reinterpret_cast<const short8*>(&f0L[1][(wave * 16 + lr) * FS + ks * 32 + kg * 8]);
    }
  }
  const int Y0 = (y >> 1) - 3;
  const float wy = (y & 1) ? 0.5f : 0.f;
  for (int v = 0; v < 8; ++v) {
    const int Y = Y0 + v;
    const bool inr = (unsigned)Y < 16u;
    __syncthreads();
    if (inr) {
#pragma unroll
      for (int i = 0; i < 3; ++i) {
        const int idx = tid + i * 256;
        if (idx < 640) {
          const int plane = idx / 320, rem = idx % 320;
          const int px = rem / 20, c16 = rem % 20;
          const short* src = (plane ? g1pbl : g1pbh) + ((size_t)n * 256 + Y * 16 + px) * 160 + c16 * 8;
          *reinterpret_cast<uint4*>(&f1L[plane][px * FS + c16 * 8]) =
              *reinterpret_cast<const uint4*>(src);
        }
      }
    }
    __syncthreads();
    if (wave < 2) {
      f32x4 aA = {0.f, 0.f, 0.f, 0.f}, aB = aA, aC = aA;
      if (inr) {
#pragma unroll
        for (int ks = 0; ks < 5; ++ks) {
          const short8 bh = *reinterpret_cast<const short8*>(&f1L[0][lr * FS + ks * 32 + kg * 8]);
          const short8 bl = *reinterpret_cast<const short8*>(&f1L[1][lr * FS + ks * 32 + kg * 8]);
          aA = __builtin_amdgcn_mfma_f32_16x16x32_bf16(a1h[ks], bh, aA, 0, 0, 0);
          aB = __builtin_amdgcn_mfma_f32_16x16x32_bf16(a1h[ks], bl, aB, 0, 0, 0);
          aC = __builtin_amdgcn_mfma_f32_16x16x32_bf16(a1l[ks], bh, aC, 0, 0, 0);
        }
      }
#pragma unroll
      for (int r = 0; r < 4; ++r)
        S1[v & 1][(wave * 16 + kg * 4 + r) * 17 + lr] = (aA[r] + aB[r]) + aC[r];
    }
    __syncthreads();
    if (v >= 1 && hi < 7) {
      const int dyi = v - 1;
      const int Xl = (xx >> 1) - 3 + hi;
      const int Xr = Xl + 1;
      const float* t0 = S1[(v - 1) & 1];
      const float* t1 = S1[v & 1];
      const float a00 = ((unsigned)Xl < 16u) ? t0[xx * 17 + Xl] : 0.f;
      const float a01 = ((unsigned)Xr < 16u) ? t0[xx * 17 + Xr] : 0.f;
      const float a10 = ((unsigned)Xl < 16u) ? t1[xx * 17 + Xl] : 0.f;
      const float a11 = ((unsigned)Xr < 16u) ? t1[xx * 17 + Xr] : 0.f;
      const float wx = (xx & 1) ? 0.5f : 0.f;
      const float val = ((1.f - wx) * ((1.f - wy) * a00 + wy * a10) +
                         wx * ((1.f - wy) * a01 + wy * a11)) * inv;
      out[obase + (size_t)(49 + hi * 7 + dyi) * 8192 + xx] = val;
    }
  }
}

// ---------------------------------------------------------------------------
extern "C" void kernel_launch(void* const* d_in, const int* in_sizes, int n_in,
                              void* d_out, int out_size, void* d_ws,
                              size_t ws_size, hipStream_t stream) {
  const float* x = (const float*)d_in[0];
  const float* w0 = (const float*)d_in[1];
  const float* w1 = (const float*)d_in[2];
  short* f0bh = (short*)d_ws;
  short* f0bl = f0bh + PL;
  short* f1bh = f0bl + PL;
  short* f1bl = f1bh + PL;
  short* g1pbh = f1bl + PL;
  short* g1pbl = g1pbh + PPL;
  short* wprep = g1pbh;  // overlapped: consumed by conv before pool writes
  float* out = (float*)d_out;

  wprep_kernel<<<1000, 256, 0, stream>>>(w0, w1, wprep);
  conv_fused<<<dim3(32, 4, 4), 256, 0, stream>>>(x, wprep, f0bh, f0bl, f1bh, f1bl);
  pool_b<<<640, 256, 0, stream>>>(f1bh, f1bl, g1pbh, g1pbl);
  corr_kernel<<<1024, 256, 0, stream>>>(f0bh, f0bl, f1bh, f1bl, g1pbh, g1pbl, out);
}

// Round 10
// 82.968 us; speedup vs baseline: 1.7166x; 1.7166x over previous
//
#include <hip/hip_runtime.h>
#include <hip/hip_bf16.h>

typedef __attribute__((ext_vector_type(8))) short short8;   // 8 bf16 (4 VGPRs)
typedef __attribute__((ext_vector_type(4))) float f32x4;    // MFMA acc

// Problem constants
static constexpr int HW = 1024;   // 32*32
static constexpr int C2 = 160;    // corr channel count
static constexpr int FS = 168;    // corr/epilogue LDS row stride in shorts (336 B)
static constexpr int KSTEPS = 10;
static constexpr size_t PL = 32ull * 1024 * 160;   // shorts per f-plane (10.49MB)
static constexpr size_t PPL = 32ull * 256 * 160;   // shorts per pooled plane
static constexpr int AIMG = 6656;  // shorts per (ks,qp) A-image (12800 B data + 512 B pad)

__device__ inline short bfh(float v) {
  __hip_bfloat16 h = __float2bfloat16(v);
  return *reinterpret_cast<short*>(&h);
}
__device__ inline float bff(short s) {
  union { unsigned u; float f; } c;
  c.u = ((unsigned)(unsigned short)s) << 16;
  return c.f;
}

// async global->LDS, 16 B per lane: per-lane global src, wave-uniform LDS base
// (HW adds lane*16 to dest). Drained by the vmcnt(0) before s_barrier.
typedef const __attribute__((address_space(1))) void* gas_t;
typedef __attribute__((address_space(3))) void* las_t;
__device__ inline void gload_lds16(const void* g, void* l) {
  __builtin_amdgcn_global_load_lds((gas_t)g, (las_t)l, 16, 0, 0);
}

// ---------------------------------------------------------------------------
// Kernel 0: pre-split w into bf16 (hi,lo), repacked per (ks,qp) as ONE
// contiguous 13312 B image matching conv's aL layout [hl 2][gr 80][kk 40]
// (+512 B zero pad) so conv stages it with 13 plain global_load_lds.
// gr<40: mat0 o=qp*40+gr; gr>=40: mat1 o=qp*40+gr-40. kk 32..39 zero.
// ---------------------------------------------------------------------------
__global__ __launch_bounds__(256)
void wprep2_kernel(const float* __restrict__ w0, const float* __restrict__ w1,
                   short* __restrict__ wp) {
  const int id = blockIdx.x * 256 + threadIdx.x;
  if (id >= KSTEPS * 4 * AIMG) return;
  const int img = id / AIMG, r = id % AIMG;
  const int ks = img >> 2, qp = img & 3;
  short outv = 0;
  if (r < 6400) {
    const int hl = r / 3200;
    const int g2 = r % 3200;
    const int gr = g2 / 40, kk = g2 % 40;
    const int mat = gr >= 40;
    const int o = qp * 40 + gr - mat * 40;
    if (kk < 32) {
      const float v = (mat ? w1 : w0)[o * 320 + ks * 32 + kk];
      const short hb = bfh(v);
      outv = hl ? bfh(v - bff(hb)) : hb;
    }
  }
  wp[id] = outv;
}

// ---------------------------------------------------------------------------
// Kernel 1: fused 1x1 convs (round-8 MFMA/epilogue/output layout, verified).
// ROUND-10 CHANGE: ALL staging via global_load_lds (zero staging VGPRs).
//  - x staged raw fp32 [f9][kk32][px32] (36 KB, 36 gloads). Global source
//    chunk pre-swizzled (chunk ^= oct<<1) so consumer reads at
//    px^(kg<<3) are 2 lanes/bank (free). fp32->h/l bf16 at the consumer.
//  - A staged from wprep2 (13 gloads, contiguous image).
//  - LDS 50176 B; per ks: issue gloads -> barrier(vmcnt drain) -> MFMA.
// ---------------------------------------------------------------------------
__global__ __launch_bounds__(256)
void conv_fused(const float* __restrict__ x, const short* __restrict__ wprep2,
                short* __restrict__ f0bh, short* __restrict__ f0bl,
                short* __restrict__ f1bh, short* __restrict__ f1bl) {
  __shared__ __align__(16) char lds[50176];
  float* xF = reinterpret_cast<float*>(lds);            // [9][32][32] fp32
  short* aL = reinterpret_cast<short*>(lds + 36864);    // [hl 2][gr 80][kk 40]
  short* tL = reinterpret_cast<short*>(lds);            // epilogue [2][64][168]

  const int pxt = blockIdx.x;  // 0..31 (y row-tile)
  const int qp = blockIdx.y;   // 0..3
  const int bb = blockIdx.z;   // 0..3
  const int tid = threadIdx.x;
  const int lane = tid & 63;
  const int wave = __builtin_amdgcn_readfirstlane(tid >> 6);
  const int lr = lane & 15, kg = lane >> 4;
  const int pxh = wave & 1;   // px half (16)
  const int fpar = wave >> 1; // frame parity: f in {fpar, fpar+2, ...}

  const int l8 = lane >> 3;   // x-gload: row (c) within octet
  const int l7 = lane & 7;    // x-gload: 16B chunk within 128B px-row
  const int px = pxh * 16 + lr;
  const int pxs = px ^ (kg << 3);  // swizzled read column

  f32x4 acc[5][5];
#pragma unroll
  for (int mt = 0; mt < 5; ++mt)
#pragma unroll
    for (int fi = 0; fi < 5; ++fi)
#pragma unroll
      for (int r = 0; r < 4; ++r) acc[mt][fi][r] = 0.f;

  // x element float offset: ((bb*320 + c)*9 + f)*1024 + pxt*32 + px
  const float* xg = x + ((size_t)(bb * 320) * 9) * 1024 + (size_t)pxt * 32;

  for (int ks = 0; ks < KSTEPS; ++ks) {
    if (ks) __syncthreads();  // previous MFMA readers done
    // ---- A: 13 gloads (block-wide), wave w handles j = w*4..w*4+3 ----
    {
      const short* src = wprep2 + (size_t)(ks * 4 + qp) * AIMG;
#pragma unroll
      for (int jj = 0; jj < 4; ++jj) {
        const int j = wave * 4 + jj;
        if (j < 13) gload_lds16(src + j * 512 + lane * 8, aL + j * 512);
      }
    }
    // ---- x: 36 gloads, wave w handles gi = w*9..w*9+8; gi = f*4 + oct ----
#pragma unroll
    for (int jj = 0; jj < 9; ++jj) {
      const int gi = wave * 9 + jj;
      const int f = gi >> 2, oct = gi & 3;
      const int c = ks * 32 + oct * 8 + l8;
      const float* src =
          xg + ((size_t)c * 9 + f) * 1024 + ((l7 ^ (oct << 1)) << 2);
      gload_lds16(src, xF + gi * 256);
    }
    __syncthreads();  // implicit vmcnt(0): all gloads landed

    // ---- MFMA phase ----
    short8 Ah[5], Al[5];
#pragma unroll
    for (int mt = 0; mt < 5; ++mt) {
      Ah[mt] = *reinterpret_cast<const short8*>(&aL[(mt * 16 + lr) * 40 + kg * 8]);
      Al[mt] = *reinterpret_cast<const short8*>(&aL[3200 + (mt * 16 + lr) * 40 + kg * 8]);
    }
#pragma unroll
    for (int fi = 0; fi < 5; ++fi) {
      const int f = 2 * fi + fpar;
      if (f < 9) {  // wave-uniform
        const float* bp = xF + f * 1024 + kg * 256 + pxs;
        float xv[8];
#pragma unroll
        for (int j = 0; j < 8; ++j) xv[j] = bp[j * 32];
        short8 Bh, Bl;
#pragma unroll
        for (int j = 0; j < 8; ++j) {
          const short h = bfh(xv[j]);
          Bh[j] = h;
          Bl[j] = bfh(xv[j] - bff(h));
        }
#pragma unroll
        for (int mt = 0; mt < 5; ++mt) {
          acc[mt][fi] = __builtin_amdgcn_mfma_f32_16x16x32_bf16(Ah[mt], Bh, acc[mt][fi], 0, 0, 0);
          acc[mt][fi] = __builtin_amdgcn_mfma_f32_16x16x32_bf16(Ah[mt], Bl, acc[mt][fi], 0, 0, 0);
          acc[mt][fi] = __builtin_amdgcn_mfma_f32_16x16x32_bf16(Al[mt], Bh, acc[mt][fi], 0, 0, 0);
        }
      }
    }
  }

  // ---- epilogue: two mat-passes through LDS transpose (round-8 verbatim) ----
#pragma unroll
  for (int m = 0; m < 2; ++m) {
    __syncthreads();  // previous readers of xF/aL/tL done
#pragma unroll
    for (int mt = 0; mt < 5; ++mt)
#pragma unroll
      for (int fi = 0; fi < 5; ++fi) {
        const int f = 2 * fi + fpar;
        const int tt = f - m;
        if (f < 9 && (unsigned)tt < 8u) {
#pragma unroll
          for (int rr = 0; rr < 4; ++rr) {
            const int gr = mt * 16 + kg * 4 + rr;
            if ((gr >= 40) == (m == 1)) {  // row belongs to this mat
              const int rowl = gr - m * 40;
              const int ql = rowl / 20, r20 = rowl % 20;
              const int c = 8 * r20 + tt;
              const int row = ql * 32 + pxh * 16 + lr;
              const float v = acc[mt][fi][rr];
              const short h = bfh(v);
              const short l = bfh(v - bff(h));
              tL[row * FS + c] = h;
              tL[10752 + row * FS + c] = l;
            }
          }
        }
      }
    __syncthreads();
    // coalesced copy-out: 2560 uint4
#pragma unroll
    for (int i = 0; i < 10; ++i) {
      const int idx = tid + i * 256;
      const int plane = idx / 1280, rem = idx % 1280;
      const int row = rem / 20, c16 = rem % 20;
      const int ql = row >> 5, pxl = row & 31;
      const int n = bb * 8 + qp * 2 + ql;
      short* dst = (m == 0) ? (plane ? f0bl : f0bh) : (plane ? f1bl : f1bh);
      *reinterpret_cast<uint4*>(dst + ((size_t)n * 1024 + pxt * 32 + pxl) * 160 + c16 * 8) =
          *reinterpret_cast<const uint4*>(&tL[plane * 10752 + row * FS + c16 * 8]);
    }
  }
}

// ---------------------------------------------------------------------------
// Kernel 2: 2x2 avg-pool on the bf16 h/l planes (unchanged)
// ---------------------------------------------------------------------------
__global__ __launch_bounds__(256)
void pool_b(const short* __restrict__ f1bh, const short* __restrict__ f1bl,
            short* __restrict__ g1pbh, short* __restrict__ g1pbl) {
  const int id = blockIdx.x * 256 + threadIdx.x;  // 32*256*20
  if (id >= 32 * 256 * 20) return;
  const int c16 = id % 20;
  const int PX = (id / 20) & 255;
  const int n = id / (20 * 256);
  const int Y = PX >> 4, X = PX & 15;
  const int r0 = Y * 64 + X * 2;
  const size_t base = ((size_t)n * 1024 + r0) * 160 + c16 * 8;
  const short8 h00 = *reinterpret_cast<const short8*>(f1bh + base);
  const short8 h01 = *reinterpret_cast<const short8*>(f1bh + base + 160);
  const short8 h10 = *reinterpret_cast<const short8*>(f1bh + base + 32 * 160);
  const short8 h11 = *reinterpret_cast<const short8*>(f1bh + base + 33 * 160);
  const short8 l00 = *reinterpret_cast<const short8*>(f1bl + base);
  const short8 l01 = *reinterpret_cast<const short8*>(f1bl + base + 160);
  const short8 l10 = *reinterpret_cast<const short8*>(f1bl + base + 32 * 160);
  const short8 l11 = *reinterpret_cast<const short8*>(f1bl + base + 33 * 160);
  short8 ho, lo;
#pragma unroll
  for (int j = 0; j < 8; ++j) {
    const float v = 0.25f * ((bff(h00[j]) + bff(l00[j])) + (bff(h01[j]) + bff(l01[j])) +
                             (bff(h10[j]) + bff(l10[j])) + (bff(h11[j]) + bff(l11[j])));
    const short h = bfh(v);
    ho[j] = h;
    lo[j] = bfh(v - bff(h));
  }
  const size_t ob = ((size_t)n * 256 + PX) * 160 + c16 * 8;
  *reinterpret_cast<short8*>(g1pbh + ob) = ho;
  *reinterpret_cast<short8*>(g1pbl + ob) = lo;
}

// ---------------------------------------------------------------------------
// Kernel 3: correlation + pyramid sampling via split-bf16 MFMA
// (unchanged from round 6 — verified; XCD swizzle kept)
// ---------------------------------------------------------------------------
__global__ __launch_bounds__(256)
void corr_kernel(const short* __restrict__ f0bh, const short* __restrict__ f0bl,
                 const short* __restrict__ f1bh, const short* __restrict__ f1bl,
                 const short* __restrict__ g1pbh, const short* __restrict__ g1pbl,
                 float* __restrict__ out) {
  __shared__ __align__(16) short f0L[2][32 * FS];
  __shared__ __align__(16) short f1L[2][32 * FS];
  __shared__ float S0[32 * 33];
  __shared__ float S1[2][32 * 17];
  const int flat = blockIdx.x;
  const int xcd = flat & 7;
  const int rr_ = flat >> 3;
  const int y = rr_ & 31;                 // 0..31
  const int n = (xcd << 2) | (rr_ >> 5);  // 0..31
  const int bb = n >> 3, q = n & 7;
  const int tid = threadIdx.x;
  const int lane = tid & 63;
  const int wave = __builtin_amdgcn_readfirstlane(tid >> 6);
  const int lr = lane & 15, kg = lane >> 4;
  const int xx = tid & 31;
  const int hi = tid >> 5;  // 0..7
  const float inv = 1.f / 160.f;
  const size_t obase = (size_t)(bb * 784 + q) * 1024 + (size_t)y * 32;

  // ---- stage f0 row: plain uint4 copies ----
#pragma unroll
  for (int i = 0; i < 5; ++i) {
    const int idx = tid + i * 256;  // < 1280
    const int plane = idx / 640, rem = idx % 640;
    const int px = rem / 20, c16 = rem % 20;
    const short* src = (plane ? f0bl : f0bh) + ((size_t)n * 1024 + y * 32 + px) * 160 + c16 * 8;
    *reinterpret_cast<uint4*>(&f0L[plane][px * FS + c16 * 8]) =
        *reinterpret_cast<const uint4*>(src);
  }
  __syncthreads();

  // ---- hoist A-fragments ----
  const int mi0 = wave >> 1, ni0 = wave & 1;
  short8 a0h[5], a0l[5];
#pragma unroll
  for (int ks = 0; ks < 5; ++ks) {
    a0h[ks] = *reinterpret_cast<const short8*>(&f0L[0][(mi0 * 16 + lr) * FS + ks * 32 + kg * 8]);
    a0l[ks] = *reinterpret_cast<const short8*>(&f0L[1][(mi0 * 16 + lr) * FS + ks * 32 + kg * 8]);
  }

  // ---- level 0 ----
  for (int dyi = 0; dyi < 7; ++dyi) {
    const int yy = y + dyi - 3;
    const bool inr = (unsigned)yy < 32u;
    __syncthreads();
    if (inr) {
#pragma unroll
      for (int i = 0; i < 5; ++i) {
        const int idx = tid + i * 256;
        const int plane = idx / 640, rem = idx % 640;
        const int px = rem / 20, c16 = rem % 20;
        const short* src = (plane ? f1bl : f1bh) + ((size_t)n * 1024 + yy * 32 + px) * 160 + c16 * 8;
        *reinterpret_cast<uint4*>(&f1L[plane][px * FS + c16 * 8]) =
            *reinterpret_cast<const uint4*>(src);
      }
    }
    __syncthreads();
    if (inr) {
      f32x4 aA = {0.f, 0.f, 0.f, 0.f}, aB = aA, aC = aA;
#pragma unroll
      for (int ks = 0; ks < 5; ++ks) {
        const short8 bh = *reinterpret_cast<const short8*>(&f1L[0][(ni0 * 16 + lr) * FS + ks * 32 + kg * 8]);
        const short8 bl = *reinterpret_cast<const short8*>(&f1L[1][(ni0 * 16 + lr) * FS + ks * 32 + kg * 8]);
        aA = __builtin_amdgcn_mfma_f32_16x16x32_bf16(a0h[ks], bh, aA, 0, 0, 0);
        aB = __builtin_amdgcn_mfma_f32_16x16x32_bf16(a0h[ks], bl, aB, 0, 0, 0);
        aC = __builtin_amdgcn_mfma_f32_16x16x32_bf16(a0l[ks], bh, aC, 0, 0, 0);
      }
#pragma unroll
      for (int r = 0; r < 4; ++r)
        S0[(mi0 * 16 + kg * 4 + r) * 33 + ni0 * 16 + lr] = (aA[r] + aB[r]) + aC[r];
    }
    __syncthreads();
    if (hi < 7) {
      const int x2 = xx + hi - 3;
      const float val = (inr && (unsigned)x2 < 32u) ? S0[xx * 33 + x2] * inv : 0.f;
      out[obase + (size_t)(hi * 7 + dyi) * 8192 + xx] = val;
    }
  }

  // ---- level 1: corner dots on pooled planes, rolling S1 + fused combine ----
  short8 a1h[5], a1l[5];
  if (wave < 2) {
#pragma unroll
    for (int ks = 0; ks < 5; ++ks) {
      a1h[ks] = *reinterpret_cast<const short8*>(&f0L[0][(wave * 16 + lr) * FS + ks * 32 + kg * 8]);
      a1l[ks] = *reinterpret_cast<const short8*>(&f0L[1][(wave * 16 + lr) * FS + ks * 32 + kg * 8]);
    }
  }
  const int Y0 = (y >> 1) - 3;
  const float wy = (y & 1) ? 0.5f : 0.f;
  for (int v = 0; v < 8; ++v) {
    const int Y = Y0 + v;
    const bool inr = (unsigned)Y < 16u;
    __syncthreads();
    if (inr) {
#pragma unroll
      for (int i = 0; i < 3; ++i) {
        const int idx = tid + i * 256;
        if (idx < 640) {
          const int plane = idx / 320, rem = idx % 320;
          const int px = rem / 20, c16 = rem % 20;
          const short* src = (plane ? g1pbl : g1pbh) + ((size_t)n * 256 + Y * 16 + px) * 160 + c16 * 8;
          *reinterpret_cast<uint4*>(&f1L[plane][px * FS + c16 * 8]) =
              *reinterpret_cast<const uint4*>(src);
        }
      }
    }
    __syncthreads();
    if (wave < 2) {
      f32x4 aA = {0.f, 0.f, 0.f, 0.f}, aB = aA, aC = aA;
      if (inr) {
#pragma unroll
        for (int ks = 0; ks < 5; ++ks) {
          const short8 bh = *reinterpret_cast<const short8*>(&f1L[0][lr * FS + ks * 32 + kg * 8]);
          const short8 bl = *reinterpret_cast<const short8*>(&f1L[1][lr * FS + ks * 32 + kg * 8]);
          aA = __builtin_amdgcn_mfma_f32_16x16x32_bf16(a1h[ks], bh, aA, 0, 0, 0);
          aB = __builtin_amdgcn_mfma_f32_16x16x32_bf16(a1h[ks], bl, aB, 0, 0, 0);
          aC = __builtin_amdgcn_mfma_f32_16x16x32_bf16(a1l[ks], bh, aC, 0, 0, 0);
        }
      }
#pragma unroll
      for (int r = 0; r < 4; ++r)
        S1[v & 1][(wave * 16 + kg * 4 + r) * 17 + lr] = (aA[r] + aB[r]) + aC[r];
    }
    __syncthreads();
    if (v >= 1 && hi < 7) {
      const int dyi = v - 1;
      const int Xl = (xx >> 1) - 3 + hi;
      const int Xr = Xl + 1;
      const float* t0 = S1[(v - 1) & 1];
      const float* t1 = S1[v & 1];
      const float a00 = ((unsigned)Xl < 16u) ? t0[xx * 17 + Xl] : 0.f;
      const float a01 = ((unsigned)Xr < 16u) ? t0[xx * 17 + Xr] : 0.f;
      const float a10 = ((unsigned)Xl < 16u) ? t1[xx * 17 + Xl] : 0.f;
      const float a11 = ((unsigned)Xr < 16u) ? t1[xx * 17 + Xr] : 0.f;
      const float wx = (xx & 1) ? 0.5f : 0.f;
      const float val = ((1.f - wx) * ((1.f - wy) * a00 + wy * a10) +
                         wx * ((1.f - wy) * a01 + wy * a11)) * inv;
      out[obase + (size_t)(49 + hi * 7 + dyi) * 8192 + xx] = val;
    }
  }
}

// ---------------------------------------------------------------------------
extern "C" void kernel_launch(void* const* d_in, const int* in_sizes, int n_in,
                              void* d_out, int out_size, void* d_ws,
                              size_t ws_size, hipStream_t stream) {
  const float* x = (const float*)d_in[0];
  const float* w0 = (const float*)d_in[1];
  const float* w1 = (const float*)d_in[2];
  short* f0bh = (short*)d_ws;
  short* f0bl = f0bh + PL;
  short* f1bh = f0bl + PL;
  short* f1bl = f1bh + PL;
  short* g1pbh = f1bl + PL;
  short* g1pbl = g1pbh + PPL;
  short* wprep2 = g1pbh;  // overlapped: consumed by conv before pool writes
  float* out = (float*)d_out;

  wprep2_kernel<<<1040, 256, 0, stream>>>(w0, w1, wprep2);
  conv_fused<<<dim3(32, 4, 4), 256, 0, stream>>>(x, wprep2, f0bh, f0bl, f1bh, f1bl);
  pool_b<<<640, 256, 0, stream>>>(f1bh, f1bl, g1pbh, g1pbl);
  corr_kernel<<<1024, 256, 0, stream>>>(f0bh, f0bl, f1bh, f1bl, g1pbh, g1pbl, out);
}